// Round 6
// baseline (861.140 us; speedup 1.0000x reference)
//
#include <hip/hip_runtime.h>
#include <cstdint>
#include <cstddef>

#define BB 4
#define NN 4096
#define DD 768
#define EE 2304      // 3*DD
#define MTOT 16384   // BB*NN
static constexpr float ATT_SCALE = 0.03608439182435161f;  // 1/sqrt(768)

typedef _Float16 v8h __attribute__((ext_vector_type(8)));
typedef _Float16 v4h __attribute__((ext_vector_type(4)));
typedef float v4f __attribute__((ext_vector_type(4)));

// Async global->LDS, 16B per lane. LDS dest = wave-uniform base + lane*16.
__device__ __forceinline__ void async_copy16(void* lds, const void* gmem) {
  __builtin_amdgcn_global_load_lds(
      (const __attribute__((address_space(1))) uint32_t*)(uintptr_t)gmem,
      (__attribute__((address_space(3))) uint32_t*)(uintptr_t)lds,
      16, 0, 0);
}

enum { EPI_QKV = 0, EPI_F16 = 1, EPI_OUT = 2, EPI_PV = 3 };

// C[M,N] = A[M,K] @ Bt[N,K]^T.  A row-major (lda), Bt n-major (ldb).
// 128x128 tile, BK=64, 256 threads = 4 waves 2x2, 4x4 16x16x32 f16 MFMA.
//
// Only B is staged through LDS (16 KB, XOR-swizzled rows so ds_read_b128 is
// conflict-free).  A fragments load DIRECTLY global->VGPR (per-lane dwordx4;
// L1 serves the 2nd wave-column's re-read, L2 serves cross-block re-reads).
// Rationale: with both operands in LDS the ds_read pipe (16 x b128 ~ 192
// cyc/iter/wave, m134) exceeds the MFMA pipe (32 x ~4.85 ~ 155 cyc).
// A-direct halves LDS-pipe demand and takes A off the barrier-drain path.
//
// R6 FIX: Bs is 1024 16B chunks -> 4 chunks/thread (i<4).  R5's i<2 left LDS
// rows 64..127 UNWRITTEN -> wc=1 waves consumed stale LDS -> NaN.
//
// EPI_PV: blockIdx.z = khalf*2 + batch; k-range [khalf*K, khalf*K+K);
//         C = c_f32 + khalf*chalf + batch*zC (plain f32 partial stores).
// Other EPIs: blockIdx.z = batch (offsets zA/zB/zC).
template <int EPI>
__global__ __launch_bounds__(256) void gemm128(
    const _Float16* __restrict__ A, int lda, size_t zA,
    const _Float16* __restrict__ Bt, int ldb, size_t zB,
    int K,
    float* __restrict__ c_f32,
    _Float16* __restrict__ c_f16,
    int ldc, size_t zC, size_t chalf,
    const float* __restrict__ bias,
    _Float16* __restrict__ q_out,
    _Float16* __restrict__ k_out,
    _Float16* __restrict__ v_out) {
  __shared__ __align__(16) _Float16 Bs[128 * 64];

  const int tid = threadIdx.x;
  const int wid = tid >> 6, lane = tid & 63;
  const int wr = wid >> 1, wc = wid & 1;       // wave grid 2x2 (64x64 each)
  const int lq = lane >> 4, lr = lane & 15;    // quad, row-in-tile
  const int m0 = blockIdx.x * 128, n0 = blockIdx.y * 128;
  const int z = blockIdx.z;
  int bidx, koff;
  if constexpr (EPI == EPI_PV) {
    bidx = z & 1;            // batch within chunk
    koff = (z >> 1) * K;     // k-half offset
  } else {
    bidx = z;
    koff = 0;
  }

  const _Float16* Ab = A + (size_t)bidx * zA + (size_t)m0 * lda + koff;
  const _Float16* Bb = Bt + (size_t)bidx * zB + (size_t)n0 * ldb + koff;

  // Per-lane A row pointers (rows wr*64 + t*16 + lr), hoisted out of the loop.
  const _Float16* Arow[4];
#pragma unroll
  for (int t = 0; t < 4; ++t)
    Arow[t] = Ab + (size_t)(wr * 64 + t * 16 + lr) * lda + lq * 8;

  v4f acc[4][4] = {};

  for (int k0 = 0; k0 < K; k0 += 64) {
    // Stage 16KB B tile: 1024 chunks of 16B, 4 per thread.  chunk c: row
    // r=c>>3; physical chunk position c&7 holds logical col-chunk (c&7)^(r&7).
#pragma unroll
    for (int i = 0; i < 4; ++i) {
      const int c = i * 256 + tid;
      const int r = c >> 3;
      const int kc = (c & 7) ^ (r & 7);
      async_copy16(Bs + (size_t)c * 8, Bb + (size_t)r * ldb + (k0 + kc * 8));
    }
    // A fragments straight from global (8 x dwordx4 per lane per iter).
    v8h af[2][4];
#pragma unroll
    for (int ks = 0; ks < 2; ++ks)
#pragma unroll
      for (int t = 0; t < 4; ++t)
        af[ks][t] = *(const v8h*)(Arow[t] + k0 + ks * 32);
    __syncthreads();  // drains B staging (and the af loads, needed now anyway)

#pragma unroll
    for (int ks = 0; ks < 2; ++ks) {
      v8h bf[4];
#pragma unroll
      for (int t = 0; t < 4; ++t) {
        const int rb = wc * 64 + t * 16 + lr;
        const int cb = ks * 4 + lq;
        bf[t] = *(const v8h*)(Bs + rb * 64 + (((cb ^ (rb & 7)) << 3)));
      }
#pragma unroll
      for (int mt = 0; mt < 4; ++mt)
#pragma unroll
        for (int nt = 0; nt < 4; ++nt)
          acc[mt][nt] = __builtin_amdgcn_mfma_f32_16x16x32_f16(
              af[ks][mt], bf[nt], acc[mt][nt], 0, 0, 0);
    }
    __syncthreads();
  }

  // Epilogue. C/D frag: col = lane&15, row = (lane>>4)*4 + reg (m89/m91).
  float* cf = nullptr;
  _Float16* ch = nullptr;
  if constexpr (EPI == EPI_PV)
    cf = c_f32 + (size_t)(z >> 1) * chalf + (size_t)bidx * zC;
  else if constexpr (EPI == EPI_OUT)
    cf = c_f32 + (size_t)bidx * zC;
  else if constexpr (EPI == EPI_F16)
    ch = c_f16 + (size_t)bidx * zC;

#pragma unroll
  for (int mt = 0; mt < 4; ++mt) {
#pragma unroll
    for (int nt = 0; nt < 4; ++nt) {
#pragma unroll
      for (int rg = 0; rg < 4; ++rg) {
        const int gm = m0 + wr * 64 + mt * 16 + lq * 4 + rg;
        const int gn = n0 + wc * 64 + nt * 16 + lr;
        float v = acc[mt][nt][rg];
        if constexpr (EPI == EPI_QKV) {
          v += bias[gn];
          if (gn < DD) {            // block-uniform branches (multiples of 128)
            q_out[(size_t)gm * DD + gn] = (_Float16)(v * ATT_SCALE);
          } else if (gn < 2 * DD) {
            k_out[(size_t)gm * DD + (gn - DD)] = (_Float16)v;
          } else {
            v_out[(size_t)gm * DD + (gn - 2 * DD)] = (_Float16)v;
          }
        } else if constexpr (EPI == EPI_F16) {
          ch[(size_t)gm * ldc + gn] = (_Float16)v;
        } else {  // EPI_PV / EPI_OUT
          cf[(size_t)gm * ldc + gn] = (EPI == EPI_OUT) ? v + bias[gn] : v;
        }
      }
    }
  }
}

// ctx f16 = half0 + half1 (split-K reduce + f32->f16 convert).
__global__ __launch_bounds__(256) void reduce_ctx(const float* __restrict__ h0,
                                                  const float* __restrict__ h1,
                                                  _Float16* __restrict__ out,
                                                  int n4) {
  int i = blockIdx.x * blockDim.x + threadIdx.x;
  if (i < n4) {
    v4f a = ((const v4f*)h0)[i];
    v4f b = ((const v4f*)h1)[i];
    v4h o;
#pragma unroll
    for (int j = 0; j < 4; ++j) o[j] = (_Float16)(a[j] + b[j]);
    ((v4h*)out)[i] = o;
  }
}

// Row softmax over f16 scores, in place.  ONE WAVE PER ROW (64 lanes x 64
// elems): shuffle-only reductions, zero block barriers, each lane rewrites
// exactly what it loaded.  Grid (NN/4, nz), 256 threads = 4 waves = 4 rows.
__global__ __launch_bounds__(256) void softmax_wave_f16(_Float16* __restrict__ S) {
  const int wid = threadIdx.x >> 6, lane = threadIdx.x & 63;
  const int row = blockIdx.x * 4 + wid;
  _Float16* p = S + (size_t)blockIdx.y * NN * NN + (size_t)row * NN;

  float f[64];
  float m = -3.0e38f;
#pragma unroll
  for (int i = 0; i < 8; ++i) {
    v8h v = ((const v8h*)p)[lane + i * 64];
#pragma unroll
    for (int j = 0; j < 8; ++j) {
      f[i * 8 + j] = (float)v[j];
      m = fmaxf(m, f[i * 8 + j]);
    }
  }
#pragma unroll
  for (int off = 32; off > 0; off >>= 1) m = fmaxf(m, __shfl_xor(m, off));

  float sum = 0.f;
#pragma unroll
  for (int i = 0; i < 64; ++i) {
    f[i] = __expf(f[i] - m);
    sum += f[i];
  }
#pragma unroll
  for (int off = 32; off > 0; off >>= 1) sum += __shfl_xor(sum, off);
  const float inv = 1.0f / sum;

#pragma unroll
  for (int i = 0; i < 8; ++i) {
    v8h o;
#pragma unroll
    for (int j = 0; j < 8; ++j) o[j] = (_Float16)(f[i * 8 + j] * inv);
    ((v8h*)p)[lane + i * 64] = o;
  }
}

__global__ __launch_bounds__(256) void cvt_f16(const float* __restrict__ in,
                                               _Float16* __restrict__ out, int n4) {
  int i = blockIdx.x * blockDim.x + threadIdx.x;
  if (i < n4) {
    v4f v = ((const v4f*)in)[i];
    v4h o;
#pragma unroll
    for (int j = 0; j < 4; ++j) o[j] = (_Float16)v[j];
    ((v4h*)out)[i] = o;
  }
}

// out[C][R] (f16) = in[R][C] (f32). Grid (C/32, R/32), 256 threads (32x8).
__global__ __launch_bounds__(256) void transpose_cvt(const float* __restrict__ in,
                                                     _Float16* __restrict__ out,
                                                     int R, int C) {
  __shared__ float tile[32][33];
  const int bx = blockIdx.x * 32;  // C base
  const int by = blockIdx.y * 32;  // R base
  const int tx = threadIdx.x & 31, ty = threadIdx.x >> 5;
#pragma unroll
  for (int i = 0; i < 32; i += 8)
    tile[ty + i][tx] = in[(size_t)(by + ty + i) * C + (bx + tx)];
  __syncthreads();
#pragma unroll
  for (int i = 0; i < 32; i += 8)
    out[(size_t)(bx + ty + i) * R + (by + tx)] = (_Float16)tile[tx][ty + i];
}

// Vt[b][d][n] = V[b][n][d], f16. Grid (DD/32, NN/32, BB).
__global__ __launch_bounds__(256) void transpose_v(const _Float16* __restrict__ in,
                                                   _Float16* __restrict__ out) {
  __shared__ _Float16 tile[32][33];
  const int b = blockIdx.z;
  const _Float16* src = in + (size_t)b * NN * DD;
  _Float16* dst = out + (size_t)b * NN * DD;
  const int bx = blockIdx.x * 32;  // DD base
  const int by = blockIdx.y * 32;  // NN base
  const int tx = threadIdx.x & 31, ty = threadIdx.x >> 5;
#pragma unroll
  for (int i = 0; i < 32; i += 8)
    tile[ty + i][tx] = src[(size_t)(by + ty + i) * DD + (bx + tx)];
  __syncthreads();
#pragma unroll
  for (int i = 0; i < 32; i += 8)
    dst[(size_t)(bx + ty + i) * NN + (by + tx)] = tile[tx][ty + i];
}

extern "C" void kernel_launch(void* const* d_in, const int* in_sizes, int n_in,
                              void* d_out, int out_size, void* d_ws, size_t ws_size,
                              hipStream_t stream) {
  const float* x = (const float*)d_in[0];      // [16384][768]
  const float* w_qkv = (const float*)d_in[1];  // [768][2304]
  const float* b_qkv = (const float*)d_in[2];  // [2304]
  const float* w_out = (const float*)d_in[3];  // [768][768]
  const float* b_out = (const float*)d_in[4];  // [768]
  float* out = (float*)d_out;                  // [16384][768] — also used as
                                               // split-K f32 partial scratch
  char* ws = (char*)d_ws;

  // ws layout, peak 164.5 MB (proven):
  _Float16* xh    = (_Float16*)(ws + 0);           // 25 MB  (dead after QKV gemm)
  _Float16* wqkvh = (_Float16*)(ws + 25165824);    // 3.5 MB [2304][768] = W^T
  _Float16* wouth = (_Float16*)(ws + 28704768);    // 1.2 MB [768][768]  = Wout^T
  _Float16* Qh    = (_Float16*)(ws + 29884416);    // 25 MB  (pre-scaled)
  _Float16* Kh    = (_Float16*)(ws + 55050240);    // 25 MB
  _Float16* Vh    = (_Float16*)(ws + 80216064);    // 25 MB  (dead after transpose)
  _Float16* Sh    = (_Float16*)(ws + 105381888);   // 64 MB  f16 scores, 2 batches
  _Float16* Vth   = (_Float16*)(ws + 0);           // reuse xh: [4][768][4096]
  _Float16* Ch    = (_Float16*)(ws + 80216064);    // reuse Vh: [16384][768] ctx

  const size_t zQK = (size_t)NN * DD;   // per-batch stride Q/K/Vt/C (f16 elems)
  const size_t zS = (size_t)NN * NN;    // per-batch stride S (f16 elems)
  const size_t zCtx = (size_t)NN * DD;  // per-batch stride ctx partial (f32)
  const size_t chalf = 2 * zCtx;        // k-half stride in d_out (f32 elems)

  // 1) precision converts / weight transposes
  cvt_f16<<<dim3((MTOT * DD / 4) / 256), 256, 0, stream>>>(x, xh, MTOT * DD / 4);
  transpose_cvt<<<dim3(EE / 32, DD / 32), 256, 0, stream>>>(w_qkv, wqkvh, DD, EE);
  transpose_cvt<<<dim3(DD / 32, DD / 32), 256, 0, stream>>>(w_out, wouth, DD, DD);

  // 2) fused QKV projection (scale folded into Q)
  gemm128<EPI_QKV><<<dim3(MTOT / 128, EE / 128), 256, 0, stream>>>(
      xh, DD, 0, wqkvh, DD, 0, DD, nullptr, nullptr, 0, 0, 0, b_qkv, Qh, Kh, Vh);

  // 3) V -> V^T for the PV gemm's n-major B operand
  transpose_v<<<dim3(DD / 32, NN / 32, BB), 256, 0, stream>>>(Vh, Vth);

  // 4) attention in 2-batch chunks: S=QK^T (f16) ; softmax ; ctx=PV split-K=2
  for (int c = 0; c < BB / 2; ++c) {
    const _Float16* Qc = Qh + (size_t)c * 2 * zQK;
    const _Float16* Kc = Kh + (size_t)c * 2 * zQK;
    const _Float16* Vtc = Vth + (size_t)c * 2 * zQK;
    gemm128<EPI_F16><<<dim3(NN / 128, NN / 128, 2), 256, 0, stream>>>(
        Qc, DD, zQK, Kc, DD, zQK, DD, nullptr, Sh, NN, zS, 0, nullptr, nullptr,
        nullptr, nullptr);
    softmax_wave_f16<<<dim3(NN / 4, 2), 256, 0, stream>>>(Sh);
    gemm128<EPI_PV><<<dim3(NN / 128, DD / 128, 4), 256, 0, stream>>>(
        Sh, NN, zS, Vtc, NN, zQK, NN / 2, out, nullptr, DD, zCtx, chalf,
        nullptr, nullptr, nullptr, nullptr);
    reduce_ctx<<<dim3((int)(chalf / 4 / 256)), 256, 0, stream>>>(
        out, out + chalf, Ch + (size_t)c * 2 * zQK, (int)(chalf / 4));
  }

  // 5) output projection (reads Ch f16; overwrites d_out with final f32+bias)
  gemm128<EPI_OUT><<<dim3(MTOT / 128, DD / 128), 256, 0, stream>>>(
      Ch, DD, 0, wouth, DD, 0, DD, out, nullptr, DD, 0, 0, b_out, nullptr,
      nullptr, nullptr);
}